// Round 2
// baseline (731.439 us; speedup 1.0000x reference)
//
#include <hip/hip_runtime.h>
#include <cstdint>

#define DD 128
#define LL 64

// ---------------- degree count ----------------
__global__ __launch_bounds__(256) void k_deg(const int* __restrict__ dst, int* __restrict__ deg, int E) {
    int e = blockIdx.x * 256 + threadIdx.x;
    if (e < E) atomicAdd(&deg[dst[e]], 1);
}

// ---------------- y = x@W1_rel^T, z = x@W1_root^T ----------------
// One thread = one node. x row in 128 VGPRs; weights are wave-uniform ->
// compiler emits s_load + v_fmac_f32 with SGPR operand. No LDS at all.
// Per wave: 16384 v_fma (32.8k cyc) with weight s_loads amortized 64x.
__global__ __launch_bounds__(256) void k1_gemm(const float* __restrict__ x,
        const float* __restrict__ Wrel, const float* __restrict__ Wroot,
        float* __restrict__ y, float* __restrict__ z, int n)
{
    int i = blockIdx.x * 256 + threadIdx.x;
    bool act = (i < n);
    int ii = act ? i : (n - 1);

    // Load x row (512B contiguous per lane) into registers.
    float4 xr[32];
    const float4* xp = (const float4*)(x + (size_t)ii * DD);
    #pragma unroll
    for (int q = 0; q < 32; ++q) xr[q] = xp[q];

    #pragma unroll 1
    for (int m = 0; m < 2; ++m) {
        const float* __restrict__ W = m ? Wroot : Wrel;
        float* __restrict__ outp = m ? z : y;
        #pragma unroll 1
        for (int og = 0; og < LL / 4; ++og) {
            const float* w0 = W + (size_t)(og * 4 + 0) * DD;
            const float* w1 = W + (size_t)(og * 4 + 1) * DD;
            const float* w2 = W + (size_t)(og * 4 + 2) * DD;
            const float* w3 = W + (size_t)(og * 4 + 3) * DD;
            float a0 = 0.f, a1 = 0.f, a2 = 0.f, a3 = 0.f;
            #pragma unroll
            for (int q = 0; q < 32; ++q) {
                float4 xq = xr[q];
                float4 v0 = *(const float4*)(w0 + q * 4);  // uniform -> s_load
                float4 v1 = *(const float4*)(w1 + q * 4);
                float4 v2 = *(const float4*)(w2 + q * 4);
                float4 v3 = *(const float4*)(w3 + q * 4);
                a0 += v0.x * xq.x + v0.y * xq.y + v0.z * xq.z + v0.w * xq.w;
                a1 += v1.x * xq.x + v1.y * xq.y + v1.z * xq.z + v1.w * xq.w;
                a2 += v2.x * xq.x + v2.y * xq.y + v2.z * xq.z + v2.w * xq.w;
                a3 += v3.x * xq.x + v3.y * xq.y + v3.z * xq.z + v3.w * xq.w;
            }
            if (act) {
                float4 r; r.x = a0; r.y = a1; r.z = a2; r.w = a3;
                *(float4*)(outp + (size_t)i * LL + og * 4) = r;
            }
        }
    }
}

// ---------------- scan (3-phase) over deg -> rowptr, cursor ----------------
__global__ __launch_bounds__(1024) void p1_blocksum(const int* __restrict__ deg, int* __restrict__ blocksum, int n) {
    __shared__ int sc[1024];
    int i = blockIdx.x * 1024 + threadIdx.x;
    sc[threadIdx.x] = (i < n) ? deg[i] : 0;
    __syncthreads();
    for (int off = 512; off > 0; off >>= 1) {
        if (threadIdx.x < off) sc[threadIdx.x] += sc[threadIdx.x + off];
        __syncthreads();
    }
    if (threadIdx.x == 0) blocksum[blockIdx.x] = sc[0];
}

__global__ void p2_scan_blocks(const int* __restrict__ blocksum, int* __restrict__ blockoff, int nb) {
    if (threadIdx.x == 0) {
        int run = 0;
        for (int j = 0; j < nb; ++j) { blockoff[j] = run; run += blocksum[j]; }
    }
}

__global__ __launch_bounds__(1024) void p3_scan(const int* __restrict__ deg, const int* __restrict__ blockoff,
        int* __restrict__ rowptr, int* __restrict__ cursor, int n)
{
    __shared__ int sc[1024];
    int i = blockIdx.x * 1024 + threadIdx.x;
    int v = (i < n) ? deg[i] : 0;
    sc[threadIdx.x] = v;
    __syncthreads();
    for (int off = 1; off < 1024; off <<= 1) {
        int add = (threadIdx.x >= off) ? sc[threadIdx.x - off] : 0;
        __syncthreads();
        sc[threadIdx.x] += add;
        __syncthreads();
    }
    if (i < n) {
        int incl = sc[threadIdx.x] + blockoff[blockIdx.x];
        rowptr[i + 1] = incl;
        cursor[i] = incl - v;
        if (i == 0) rowptr[0] = 0;
    }
}

// ---------------- CSR scatter ----------------
__global__ __launch_bounds__(256) void k2c_scatter(const int* __restrict__ src, const int* __restrict__ dst,
        int* __restrict__ cursor, int* __restrict__ csr, int E)
{
    int e = blockIdx.x * 256 + threadIdx.x;
    if (e < E) {
        int d = dst[e];
        int pos = atomicAdd(&cursor[d], 1);
        csr[pos] = src[e];
    }
}

// ---------------- layer-1 aggregate + h + s,t (one wave per node) ----------------
__global__ __launch_bounds__(256) void k3_agg(const float* __restrict__ y, const float* __restrict__ z,
        const int* __restrict__ rowptr, const int* __restrict__ csr,
        const float* __restrict__ b1, const float* __restrict__ w2rel, const float* __restrict__ w2root,
        float* __restrict__ s, float* __restrict__ t, int n)
{
    int wave = threadIdx.x >> 6, lane = threadIdx.x & 63;
    int i = blockIdx.x * 4 + wave;
    if (i >= n) return;
    int st = rowptr[i], en = rowptr[i + 1];
    float acc = 0.f;
    for (int e = st; e < en; ++e) {
        int sj = csr[e];
        acc += y[(size_t)sj * LL + lane];   // coalesced 256B row gather
    }
    float h = acc + z[(size_t)i * LL + lane] + b1[lane];
    h = h > 0.f ? h : 0.2f * h;             // leaky_relu(0.2)
    float sv = h * w2rel[lane];
    float tv = h * w2root[lane];
    #pragma unroll
    for (int o = 32; o >= 1; o >>= 1) {
        sv += __shfl_xor(sv, o, 64);
        tv += __shfl_xor(tv, o, 64);
    }
    if (lane == 0) { s[i] = sv; t[i] = tv; }
}

// ---------------- gate logits ----------------
__global__ __launch_bounds__(256) void k5_gate(const float* __restrict__ s, const float* __restrict__ t,
        const int* __restrict__ rowptr, const int* __restrict__ csr, const float* __restrict__ b2,
        float* __restrict__ g, int n)
{
    int i = blockIdx.x * 256 + threadIdx.x;
    if (i >= n) return;
    float acc = b2[0] + t[i];
    int st = rowptr[i], en = rowptr[i + 1];
    for (int e = st; e < en; ++e) acc += s[csr[e]];
    g[i] = acc;
}

// ---------------- softmax reductions ----------------
__global__ __launch_bounds__(256) void k6_max(const float* __restrict__ g, float* __restrict__ pmax, int n) {
    __shared__ float sc[256];
    float m = -3.402823466e38f;
    for (int i = blockIdx.x * 256 + threadIdx.x; i < n; i += gridDim.x * 256)
        m = fmaxf(m, g[i]);
    sc[threadIdx.x] = m;
    __syncthreads();
    for (int off = 128; off > 0; off >>= 1) {
        if (threadIdx.x < off) sc[threadIdx.x] = fmaxf(sc[threadIdx.x], sc[threadIdx.x + off]);
        __syncthreads();
    }
    if (threadIdx.x == 0) pmax[blockIdx.x] = sc[0];
}

__global__ __launch_bounds__(256) void k6_maxfin(const float* __restrict__ pmax, float* __restrict__ scalars) {
    __shared__ float sc[256];
    sc[threadIdx.x] = pmax[threadIdx.x];
    __syncthreads();
    for (int off = 128; off > 0; off >>= 1) {
        if (threadIdx.x < off) sc[threadIdx.x] = fmaxf(sc[threadIdx.x], sc[threadIdx.x + off]);
        __syncthreads();
    }
    if (threadIdx.x == 0) scalars[0] = sc[0];
}

__global__ __launch_bounds__(256) void k6_sumexp(const float* __restrict__ g, float* __restrict__ scalars, int n) {
    __shared__ float sc[256];
    float m = scalars[0];
    float local = 0.f;
    for (int i = blockIdx.x * 256 + threadIdx.x; i < n; i += gridDim.x * 256)
        local += expf(g[i] - m);
    sc[threadIdx.x] = local;
    __syncthreads();
    for (int off = 128; off > 0; off >>= 1) {
        if (threadIdx.x < off) sc[threadIdx.x] += sc[threadIdx.x + off];
        __syncthreads();
    }
    if (threadIdx.x == 0) atomicAdd(&scalars[1], sc[0]);
}

// ---------------- out[d] = sum_i softmax(g)_i * x[i,d] ----------------
__global__ __launch_bounds__(256) void k6_out(const float* __restrict__ x, const float* __restrict__ g,
        const float* __restrict__ scalars, float* __restrict__ out, int n)
{
    __shared__ float acc_s[4][DD];
    int wave = threadIdx.x >> 6, lane = threadIdx.x & 63;
    float m = scalars[0];
    float invZ = 1.0f / scalars[1];
    float a0 = 0.f, a1 = 0.f;
    int gw = blockIdx.x * 4 + wave;
    int nw = gridDim.x * 4;
    for (int i = gw; i < n; i += nw) {
        float w = expf(g[i] - m) * invZ;
        a0 += w * x[(size_t)i * DD + lane];
        a1 += w * x[(size_t)i * DD + 64 + lane];
    }
    acc_s[wave][lane] = a0;
    acc_s[wave][lane + 64] = a1;
    __syncthreads();
    if (wave == 0) {
        float v0 = acc_s[0][lane] + acc_s[1][lane] + acc_s[2][lane] + acc_s[3][lane];
        float v1 = acc_s[0][lane + 64] + acc_s[1][lane + 64] + acc_s[2][lane + 64] + acc_s[3][lane + 64];
        atomicAdd(&out[lane], v0);
        atomicAdd(&out[lane + 64], v1);
    }
}

extern "C" void kernel_launch(void* const* d_in, const int* in_sizes, int n_in,
                              void* d_out, int out_size, void* d_ws, size_t ws_size,
                              hipStream_t stream)
{
    const float* x      = (const float*)d_in[0];
    const int*   eidx   = (const int*)d_in[1];
    const float* W1rel  = (const float*)d_in[2];
    const float* b1     = (const float*)d_in[3];
    const float* W1root = (const float*)d_in[4];
    const float* W2rel  = (const float*)d_in[5];
    const float* b2     = (const float*)d_in[6];
    const float* W2root = (const float*)d_in[7];
    float* out = (float*)d_out;

    int n = in_sizes[0] / DD;
    int E = in_sizes[1] / 2;
    const int* src = eidx;
    const int* dstp = eidx + E;

    char* ws = (char*)d_ws;
    size_t off = 0;
    auto alloc = [&](size_t bytes) -> char* {
        char* p = ws + off;
        off = (off + bytes + 255) & ~(size_t)255;
        return p;
    };
    float* y      = (float*)alloc((size_t)n * LL * 4);
    float* z      = (float*)alloc((size_t)n * LL * 4);
    int*   deg    = (int*)  alloc((size_t)n * 4);
    int*   rowptr = (int*)  alloc((size_t)(n + 1) * 4);
    int*   cursor = (int*)  alloc((size_t)n * 4);
    int*   csr    = (int*)  alloc((size_t)E * 4);
    float* s      = (float*)alloc((size_t)n * 4);
    float* t      = (float*)alloc((size_t)n * 4);
    float* g      = (float*)alloc((size_t)n * 4);
    int NB = (n + 1023) / 1024;
    int* blocksum = (int*)alloc((size_t)NB * 4);
    int* blockoff = (int*)alloc((size_t)NB * 4);
    float* pmax   = (float*)alloc(256 * 4);
    float* scalars= (float*)alloc(2 * 4);
    (void)ws_size; (void)n_in;

    hipMemsetAsync(deg, 0, (size_t)n * 4, stream);
    hipMemsetAsync(scalars, 0, 8, stream);
    hipMemsetAsync(d_out, 0, (size_t)out_size * 4, stream);

    k_deg<<<(E + 255) / 256, 256, 0, stream>>>(dstp, deg, E);
    k1_gemm<<<(n + 255) / 256, 256, 0, stream>>>(x, W1rel, W1root, y, z, n);
    p1_blocksum<<<NB, 1024, 0, stream>>>(deg, blocksum, n);
    p2_scan_blocks<<<1, 64, 0, stream>>>(blocksum, blockoff, NB);
    p3_scan<<<NB, 1024, 0, stream>>>(deg, blockoff, rowptr, cursor, n);
    k2c_scatter<<<(E + 255) / 256, 256, 0, stream>>>(src, dstp, cursor, csr, E);
    k3_agg<<<(n + 3) / 4, 256, 0, stream>>>(y, z, rowptr, csr, b1, W2rel, W2root, s, t, n);
    k5_gate<<<(n + 255) / 256, 256, 0, stream>>>(s, t, rowptr, csr, b2, g, n);
    k6_max<<<256, 256, 0, stream>>>(g, pmax, n);
    k6_maxfin<<<1, 256, 0, stream>>>(pmax, scalars);
    k6_sumexp<<<256, 256, 0, stream>>>(g, scalars, n);
    k6_out<<<512, 256, 0, stream>>>(x, g, scalars, out, n);
}

// Round 3
// 598.502 us; speedup vs baseline: 1.2221x; 1.2221x over previous
//
#include <hip/hip_runtime.h>
#include <cstdint>

#define DD 128
#define LL 64

// ---------------- degree count ----------------
__global__ __launch_bounds__(256) void k_deg(const int* __restrict__ dst, int* __restrict__ deg, int E) {
    int e = blockIdx.x * 256 + threadIdx.x;
    if (e < E) atomicAdd(&deg[dst[e]], 1);
}

// ---------------- y = x@W1_rel^T, z = x@W1_root^T ----------------
// One thread = one node. Accumulators for all 128 outputs live in VGPRs
// (written every iteration -> regalloc keeps them resident, unlike the
// round-2 x-row array which spilled). x is streamed 16B per k-chunk;
// weights are wave-uniform -> s_load, amortized across 64 lanes.
// Floor: 16384 v_fma x 2cyc/wave; chip-level = ~21us.
__global__ __launch_bounds__(256, 1) void k1_gemm(const float* __restrict__ x,
        const float* __restrict__ Wrel, const float* __restrict__ Wroot,
        float* __restrict__ y, float* __restrict__ z, int n)
{
    int i = blockIdx.x * 256 + threadIdx.x;
    bool act = (i < n);
    int ii = act ? i : (n - 1);
    const float4* xp = (const float4*)(x + (size_t)ii * DD);

    float accY[LL], accZ[LL];
    #pragma unroll
    for (int o = 0; o < LL; ++o) { accY[o] = 0.f; accZ[o] = 0.f; }

    #pragma unroll 1
    for (int q = 0; q < DD / 4; ++q) {
        float4 xq = xp[q];
        const float4* wr = (const float4*)(Wrel + q * 4);   // uniform address
        const float4* wz = (const float4*)(Wroot + q * 4);  // -> s_load
        #pragma unroll
        for (int o = 0; o < LL; ++o) {
            float4 a = wr[o * (DD / 4)];
            float4 b = wz[o * (DD / 4)];
            accY[o] += a.x * xq.x + a.y * xq.y + a.z * xq.z + a.w * xq.w;
            accZ[o] += b.x * xq.x + b.y * xq.y + b.z * xq.z + b.w * xq.w;
        }
    }

    if (act) {
        float4* yp = (float4*)(y + (size_t)i * LL);
        float4* zp = (float4*)(z + (size_t)i * LL);
        #pragma unroll
        for (int og = 0; og < LL / 4; ++og) {
            float4 r;
            r.x = accY[og * 4 + 0]; r.y = accY[og * 4 + 1];
            r.z = accY[og * 4 + 2]; r.w = accY[og * 4 + 3];
            yp[og] = r;
            float4 r2;
            r2.x = accZ[og * 4 + 0]; r2.y = accZ[og * 4 + 1];
            r2.z = accZ[og * 4 + 2]; r2.w = accZ[og * 4 + 3];
            zp[og] = r2;
        }
    }
}

// ---------------- scan (3-phase) over deg -> rowptr, cursor ----------------
__global__ __launch_bounds__(1024) void p1_blocksum(const int* __restrict__ deg, int* __restrict__ blocksum, int n) {
    __shared__ int sc[1024];
    int i = blockIdx.x * 1024 + threadIdx.x;
    sc[threadIdx.x] = (i < n) ? deg[i] : 0;
    __syncthreads();
    for (int off = 512; off > 0; off >>= 1) {
        if (threadIdx.x < off) sc[threadIdx.x] += sc[threadIdx.x + off];
        __syncthreads();
    }
    if (threadIdx.x == 0) blocksum[blockIdx.x] = sc[0];
}

__global__ void p2_scan_blocks(const int* __restrict__ blocksum, int* __restrict__ blockoff, int nb) {
    if (threadIdx.x == 0) {
        int run = 0;
        for (int j = 0; j < nb; ++j) { blockoff[j] = run; run += blocksum[j]; }
    }
}

__global__ __launch_bounds__(1024) void p3_scan(const int* __restrict__ deg, const int* __restrict__ blockoff,
        int* __restrict__ rowptr, int* __restrict__ cursor, int n)
{
    __shared__ int sc[1024];
    int i = blockIdx.x * 1024 + threadIdx.x;
    int v = (i < n) ? deg[i] : 0;
    sc[threadIdx.x] = v;
    __syncthreads();
    for (int off = 1; off < 1024; off <<= 1) {
        int add = (threadIdx.x >= off) ? sc[threadIdx.x - off] : 0;
        __syncthreads();
        sc[threadIdx.x] += add;
        __syncthreads();
    }
    if (i < n) {
        int incl = sc[threadIdx.x] + blockoff[blockIdx.x];
        rowptr[i + 1] = incl;
        cursor[i] = incl - v;
        if (i == 0) rowptr[0] = 0;
    }
}

// ---------------- CSR scatter ----------------
__global__ __launch_bounds__(256) void k2c_scatter(const int* __restrict__ src, const int* __restrict__ dst,
        int* __restrict__ cursor, int* __restrict__ csr, int E)
{
    int e = blockIdx.x * 256 + threadIdx.x;
    if (e < E) {
        int d = dst[e];
        int pos = atomicAdd(&cursor[d], 1);
        csr[pos] = src[e];
    }
}

// ---------------- layer-1 aggregate + h + s,t (one wave per node) ----------------
__global__ __launch_bounds__(256) void k3_agg(const float* __restrict__ y, const float* __restrict__ z,
        const int* __restrict__ rowptr, const int* __restrict__ csr,
        const float* __restrict__ b1, const float* __restrict__ w2rel, const float* __restrict__ w2root,
        float* __restrict__ s, float* __restrict__ t, int n)
{
    int wave = threadIdx.x >> 6, lane = threadIdx.x & 63;
    int i = blockIdx.x * 4 + wave;
    if (i >= n) return;
    int st = rowptr[i], en = rowptr[i + 1];
    float acc = 0.f;
    for (int e = st; e < en; ++e) {
        int sj = csr[e];
        acc += y[(size_t)sj * LL + lane];   // coalesced 256B row gather
    }
    float h = acc + z[(size_t)i * LL + lane] + b1[lane];
    h = h > 0.f ? h : 0.2f * h;             // leaky_relu(0.2)
    float sv = h * w2rel[lane];
    float tv = h * w2root[lane];
    #pragma unroll
    for (int o = 32; o >= 1; o >>= 1) {
        sv += __shfl_xor(sv, o, 64);
        tv += __shfl_xor(tv, o, 64);
    }
    if (lane == 0) { s[i] = sv; t[i] = tv; }
}

// ---------------- gate logits ----------------
__global__ __launch_bounds__(256) void k5_gate(const float* __restrict__ s, const float* __restrict__ t,
        const int* __restrict__ rowptr, const int* __restrict__ csr, const float* __restrict__ b2,
        float* __restrict__ g, int n)
{
    int i = blockIdx.x * 256 + threadIdx.x;
    if (i >= n) return;
    float acc = b2[0] + t[i];
    int st = rowptr[i], en = rowptr[i + 1];
    for (int e = st; e < en; ++e) acc += s[csr[e]];
    g[i] = acc;
}

// ---------------- softmax reductions ----------------
__global__ __launch_bounds__(256) void k6_max(const float* __restrict__ g, float* __restrict__ pmax, int n) {
    __shared__ float sc[256];
    float m = -3.402823466e38f;
    for (int i = blockIdx.x * 256 + threadIdx.x; i < n; i += gridDim.x * 256)
        m = fmaxf(m, g[i]);
    sc[threadIdx.x] = m;
    __syncthreads();
    for (int off = 128; off > 0; off >>= 1) {
        if (threadIdx.x < off) sc[threadIdx.x] = fmaxf(sc[threadIdx.x], sc[threadIdx.x + off]);
        __syncthreads();
    }
    if (threadIdx.x == 0) pmax[blockIdx.x] = sc[0];
}

__global__ __launch_bounds__(256) void k6_maxfin(const float* __restrict__ pmax, float* __restrict__ scalars) {
    __shared__ float sc[256];
    sc[threadIdx.x] = pmax[threadIdx.x];
    __syncthreads();
    for (int off = 128; off > 0; off >>= 1) {
        if (threadIdx.x < off) sc[threadIdx.x] = fmaxf(sc[threadIdx.x], sc[threadIdx.x + off]);
        __syncthreads();
    }
    if (threadIdx.x == 0) scalars[0] = sc[0];
}

__global__ __launch_bounds__(256) void k6_sumexp(const float* __restrict__ g, float* __restrict__ scalars, int n) {
    __shared__ float sc[256];
    float m = scalars[0];
    float local = 0.f;
    for (int i = blockIdx.x * 256 + threadIdx.x; i < n; i += gridDim.x * 256)
        local += expf(g[i] - m);
    sc[threadIdx.x] = local;
    __syncthreads();
    for (int off = 128; off > 0; off >>= 1) {
        if (threadIdx.x < off) sc[threadIdx.x] += sc[threadIdx.x + off];
        __syncthreads();
    }
    if (threadIdx.x == 0) atomicAdd(&scalars[1], sc[0]);
}

// ---------------- out[d] = sum_i softmax(g)_i * x[i,d] ----------------
__global__ __launch_bounds__(256) void k6_out(const float* __restrict__ x, const float* __restrict__ g,
        const float* __restrict__ scalars, float* __restrict__ out, int n)
{
    __shared__ float acc_s[4][DD];
    int wave = threadIdx.x >> 6, lane = threadIdx.x & 63;
    float m = scalars[0];
    float invZ = 1.0f / scalars[1];
    float a0 = 0.f, a1 = 0.f;
    int gw = blockIdx.x * 4 + wave;
    int nw = gridDim.x * 4;
    for (int i = gw; i < n; i += nw) {
        float w = expf(g[i] - m) * invZ;
        a0 += w * x[(size_t)i * DD + lane];
        a1 += w * x[(size_t)i * DD + 64 + lane];
    }
    acc_s[wave][lane] = a0;
    acc_s[wave][lane + 64] = a1;
    __syncthreads();
    if (wave == 0) {
        float v0 = acc_s[0][lane] + acc_s[1][lane] + acc_s[2][lane] + acc_s[3][lane];
        float v1 = acc_s[0][lane + 64] + acc_s[1][lane + 64] + acc_s[2][lane + 64] + acc_s[3][lane + 64];
        atomicAdd(&out[lane], v0);
        atomicAdd(&out[lane + 64], v1);
    }
}

extern "C" void kernel_launch(void* const* d_in, const int* in_sizes, int n_in,
                              void* d_out, int out_size, void* d_ws, size_t ws_size,
                              hipStream_t stream)
{
    const float* x      = (const float*)d_in[0];
    const int*   eidx   = (const int*)d_in[1];
    const float* W1rel  = (const float*)d_in[2];
    const float* b1     = (const float*)d_in[3];
    const float* W1root = (const float*)d_in[4];
    const float* W2rel  = (const float*)d_in[5];
    const float* b2     = (const float*)d_in[6];
    const float* W2root = (const float*)d_in[7];
    float* out = (float*)d_out;

    int n = in_sizes[0] / DD;
    int E = in_sizes[1] / 2;
    const int* src = eidx;
    const int* dstp = eidx + E;

    char* ws = (char*)d_ws;
    size_t off = 0;
    auto alloc = [&](size_t bytes) -> char* {
        char* p = ws + off;
        off = (off + bytes + 255) & ~(size_t)255;
        return p;
    };
    float* y      = (float*)alloc((size_t)n * LL * 4);
    float* z      = (float*)alloc((size_t)n * LL * 4);
    int*   deg    = (int*)  alloc((size_t)n * 4);
    int*   rowptr = (int*)  alloc((size_t)(n + 1) * 4);
    int*   cursor = (int*)  alloc((size_t)n * 4);
    int*   csr    = (int*)  alloc((size_t)E * 4);
    float* s      = (float*)alloc((size_t)n * 4);
    float* t      = (float*)alloc((size_t)n * 4);
    float* g      = (float*)alloc((size_t)n * 4);
    int NB = (n + 1023) / 1024;
    int* blocksum = (int*)alloc((size_t)NB * 4);
    int* blockoff = (int*)alloc((size_t)NB * 4);
    float* pmax   = (float*)alloc(256 * 4);
    float* scalars= (float*)alloc(2 * 4);
    (void)ws_size; (void)n_in;

    hipMemsetAsync(deg, 0, (size_t)n * 4, stream);
    hipMemsetAsync(scalars, 0, 8, stream);
    hipMemsetAsync(d_out, 0, (size_t)out_size * 4, stream);

    k_deg<<<(E + 255) / 256, 256, 0, stream>>>(dstp, deg, E);
    k1_gemm<<<(n + 255) / 256, 256, 0, stream>>>(x, W1rel, W1root, y, z, n);
    p1_blocksum<<<NB, 1024, 0, stream>>>(deg, blocksum, n);
    p2_scan_blocks<<<1, 64, 0, stream>>>(blocksum, blockoff, NB);
    p3_scan<<<NB, 1024, 0, stream>>>(deg, blockoff, rowptr, cursor, n);
    k2c_scatter<<<(E + 255) / 256, 256, 0, stream>>>(src, dstp, cursor, csr, E);
    k3_agg<<<(n + 3) / 4, 256, 0, stream>>>(y, z, rowptr, csr, b1, W2rel, W2root, s, t, n);
    k5_gate<<<(n + 255) / 256, 256, 0, stream>>>(s, t, rowptr, csr, b2, g, n);
    k6_max<<<256, 256, 0, stream>>>(g, pmax, n);
    k6_maxfin<<<1, 256, 0, stream>>>(pmax, scalars);
    k6_sumexp<<<256, 256, 0, stream>>>(g, scalars, n);
    k6_out<<<512, 256, 0, stream>>>(x, g, scalars, out, n);
}